// Round 12
// baseline (1052.108 us; speedup 1.0000x reference)
//
#include <hip/hip_runtime.h>

#define EPSf 1e-5f

// Hand-rolled bf16 (round-to-nearest-even) for ws intermediates.
static __device__ __forceinline__ unsigned short f32_to_bf16(float f) {
    unsigned int u = __float_as_uint(f);
    unsigned int r = (u + 0x7FFFu + ((u >> 16) & 1u)) >> 16;
    return (unsigned short)r;
}
static __device__ __forceinline__ float bf16_to_f32(unsigned short h) {
    return __uint_as_float(((unsigned int)h) << 16);
}

// 3x3 conv (pad=1) + BN + ReLU, BN folded inline from raw params.
// Tile: 16x8 pixels, 32 of 64 c_out per block. grid = (12, 24, B*2), block = 128.
// UNCHANGED from the passing round-9 version.
__global__ __launch_bounds__(128) void conv3x3_bn_relu(
    const float* __restrict__ in,    // [B,64,192,192] f32
    const float* __restrict__ wgt,   // [64,64,3,3]
    const float* __restrict__ bias,  // [64]
    const float* __restrict__ bn_g, const float* __restrict__ bn_be,
    const float* __restrict__ bn_m, const float* __restrict__ bn_v,
    unsigned short* __restrict__ out)  // [B,64,192,192] bf16 bits (workspace)
{
    __shared__ float tile[180];      // 10 rows x 18 cols
    const int t  = threadIdx.x;
    const int tx = t & 15, ty = t >> 4;
    const int x0 = blockIdx.x << 4, y0 = blockIdx.y << 3;
    const int hf = blockIdx.z & 1, b = blockIdx.z >> 1;
    const int x = x0 + tx, y = y0 + ty;
    const int cobase = hf << 5;

    float acc[32];
#pragma unroll
    for (int i = 0; i < 32; ++i) acc[i] = 0.f;

    const int r0 = t / 18, q0 = t - r0 * 18;
    const int t1 = t + 128;
    const int r1 = t1 / 18, q1 = t1 - r1 * 18;
    const int gy0 = y0 - 1 + r0, gx0 = x0 - 1 + q0;
    const int gy1 = y0 - 1 + r1, gx1 = x0 - 1 + q1;
    const bool ok0 = (gy0 >= 0 && gy0 < 192 && gx0 >= 0 && gx0 < 192);
    const bool ok1 = (t1 < 180) && (gy1 >= 0 && gy1 < 192 && gx1 >= 0 && gx1 < 192);
    const float* inb = in + (size_t)b * 64 * 36864;

    for (int ci = 0; ci < 64; ++ci) {
        const float* inc = inb + (size_t)ci * 36864;
        tile[t] = ok0 ? inc[gy0 * 192 + gx0] : 0.f;
        if (t1 < 180) tile[t1] = ok1 ? inc[gy1 * 192 + gx1] : 0.f;
        __syncthreads();

        float v[9];
#pragma unroll
        for (int i = 0; i < 3; ++i)
#pragma unroll
            for (int j = 0; j < 3; ++j)
                v[i * 3 + j] = tile[(ty + i) * 18 + tx + j];

        const float* wp = wgt + ((size_t)cobase * 64 + ci) * 9;
#pragma unroll
        for (int co = 0; co < 32; ++co)
#pragma unroll
            for (int k = 0; k < 9; ++k)
                acc[co] = fmaf(wp[co * 576 + k], v[k], acc[co]);
        __syncthreads();
    }

    size_t ob = (size_t)b * 64 * 36864 + (size_t)y * 192 + x;
#pragma unroll
    for (int co = 0; co < 32; ++co) {
        int c = cobase + co;
        float inv = bn_g[c] / sqrtf(bn_v[c] + EPSf);
        float sh  = (bias[c] - bn_m[c]) * inv + bn_be[c];
        float r = fmaf(acc[co], inv, sh);
        out[ob + (size_t)c * 36864] = f32_to_bf16(r > 0.f ? r : 0.f);
    }
}

// Fused corr + 1x1 conv, v2: channel-split across wave-pairs.
// Block = 256 threads (4 waves). h = t>>7 owns channels h*32..h*32+31 (wave-uniform).
// Phase 1: each half accumulates partial corr[81] for its 128-px tile over its 32 ch.
//          Windows win[h][8ch][16][25] staged in LDS (stride 25 kills conflicts).
// Reduce:  corrbuf[128][85] f32 overlays the (dead) windows; h0 writes, h1 adds.
// Phase 2: thread (px=t&127, half h) computes c_out h*32..h*32+31: 81 corr terms
//          from LDS (stride-85 = conflict-free) + 64 f1 terms from registers.
// grid = (12, 24, B), block = 256.
__global__ __launch_bounds__(256) void corr_conv1x1_bn_relu(
    const unsigned short* __restrict__ f1, const unsigned short* __restrict__ f2,
    const float* __restrict__ qw,    // [64][145]
    const float* __restrict__ qb,
    const float* __restrict__ qg, const float* __restrict__ qbe,
    const float* __restrict__ qm, const float* __restrict__ qv,
    float* __restrict__ out)         // [B,64,192,192] f32
{
    __shared__ float lds[10880];     // 43.5 KB: win[2][8][16][25]=6400f, then corrbuf[128][85]=10880f
    const int t  = threadIdx.x;
    const int h  = t >> 7;           // channel half (wave-uniform: waves 0-1 -> 0, 2-3 -> 1)
    const int pt = t & 127;          // pixel id in 16x8 tile
    const int tx = pt & 15, ty = pt >> 4;
    const int x0 = blockIdx.x << 4, y0 = blockIdx.y << 3;
    const int b  = blockIdx.z;
    const int x = x0 + tx, y = y0 + ty;
    const unsigned short* f1b = f1 + (size_t)b * 64 * 36864;
    const unsigned short* f2b = f2 + (size_t)b * 64 * 36864;

    float corr[81];
#pragma unroll
    for (int i = 0; i < 81; ++i) corr[i] = 0.f;

    const int hbase = h * 3200;      // win[h] base (floats)

    for (int cs = 0; cs < 32; cs += 8) {
        // stage win[h]: 8 channels (h*32+cs ..), rows y0-4..y0+11, cols x0-4..x0+19
#pragma unroll
        for (int k = 0; k < 24; ++k) {
            int i = pt + (k << 7);               // 0..3071
            int cc = i / 384, rem = i - cc * 384;
            int r = rem / 24, col = rem - r * 24;
            int gy = y0 - 4 + r, gx = x0 - 4 + col;
            float vv = 0.f;
            if (gy >= 0 && gy < 192 && gx >= 0 && gx < 192)
                vv = bf16_to_f32(f2b[(size_t)(h * 32 + cs + cc) * 36864 + gy * 192 + gx]);
            lds[hbase + cc * 400 + r * 25 + col] = vv;
        }
        __syncthreads();

#pragma unroll
        for (int cc = 0; cc < 8; ++cc) {
            float f1v = bf16_to_f32(f1b[(size_t)(h * 32 + cs + cc) * 36864 + y * 192 + x]);
            const float* sp = &lds[hbase + cc * 400 + ty * 25 + tx];
#pragma unroll
            for (int dy = 0; dy < 9; ++dy)
#pragma unroll
                for (int dx = 0; dx < 9; ++dx)
                    corr[dx * 9 + dy] = fmaf(f1v, sp[dy * 25 + dx], corr[dx * 9 + dy]);
        }
        __syncthreads();
    }

    // reduce the two channel-halves into corrbuf (overlays dead windows)
    if (h == 0) {
#pragma unroll
        for (int d = 0; d < 81; ++d) lds[pt * 85 + d] = corr[d] * 0.125f;
    }
    __syncthreads();
    if (h == 1) {
#pragma unroll
        for (int d = 0; d < 81; ++d) lds[pt * 85 + d] += corr[d] * 0.125f;
    }
    __syncthreads();

    // phase 2: 1x1 conv (145->64) + BN + ReLU; half h does c_out h*32..h*32+31
    float f1r[64];
#pragma unroll
    for (int c = 0; c < 64; ++c)
        f1r[c] = bf16_to_f32(f1b[(size_t)c * 36864 + y * 192 + x]);

    const float* cb = &lds[pt * 85];
    size_t ob = (size_t)b * 64 * 36864 + (size_t)y * 192 + x;
#pragma unroll 2
    for (int j = 0; j < 32; ++j) {
        int co = h * 32 + j;
        const float* wp = qw + co * 145;         // wave-uniform -> scalar loads
        float a0 = 0.f, a1 = 0.f, a2 = 0.f, a3 = 0.f;
#pragma unroll
        for (int d = 0; d < 80; d += 4) {
            a0 = fmaf(wp[d + 0], cb[d + 0], a0);
            a1 = fmaf(wp[d + 1], cb[d + 1], a1);
            a2 = fmaf(wp[d + 2], cb[d + 2], a2);
            a3 = fmaf(wp[d + 3], cb[d + 3], a3);
        }
        a0 = fmaf(wp[80], cb[80], a0);
#pragma unroll
        for (int c = 0; c < 64; c += 4) {
            a0 = fmaf(wp[81 + c + 0], f1r[c + 0], a0);
            a1 = fmaf(wp[81 + c + 1], f1r[c + 1], a1);
            a2 = fmaf(wp[81 + c + 2], f1r[c + 2], a2);
            a3 = fmaf(wp[81 + c + 3], f1r[c + 3], a3);
        }
        float acc = (a0 + a1) + (a2 + a3);
        float inv = qg[co] / sqrtf(qv[co] + EPSf);
        float sh  = (qb[co] - qm[co]) * inv + qbe[co];
        float r = fmaf(acc, inv, sh);
        out[ob + (size_t)co * 36864] = (r > 0.f ? r : 0.f);
    }
}

extern "C" void kernel_launch(void* const* d_in, const int* in_sizes, int n_in,
                              void* d_out, int out_size, void* d_ws, size_t ws_size,
                              hipStream_t stream) {
    float* out = (float*)d_out;   // reference output dtype is float32

    // ws: f1 | f2, each 4*64*192*192 bf16 = 18.87 MB (total 37.75 MB)
    unsigned short* f1 = (unsigned short*)d_ws;
    unsigned short* f2 = f1 + (size_t)4 * 64 * 36864;

    dim3 cgrid(12, 24, 8);
    conv3x3_bn_relu<<<cgrid, 128, 0, stream>>>(
        (const float*)d_in[0], (const float*)d_in[2], (const float*)d_in[3],
        (const float*)d_in[4], (const float*)d_in[5], (const float*)d_in[6],
        (const float*)d_in[7], f1);
    conv3x3_bn_relu<<<cgrid, 128, 0, stream>>>(
        (const float*)d_in[1], (const float*)d_in[8], (const float*)d_in[9],
        (const float*)d_in[10], (const float*)d_in[11], (const float*)d_in[12],
        (const float*)d_in[13], f2);

    dim3 ggrid(12, 24, 4);
    corr_conv1x1_bn_relu<<<ggrid, 256, 0, stream>>>(
        f1, f2,
        (const float*)d_in[14], (const float*)d_in[15], (const float*)d_in[16],
        (const float*)d_in[17], (const float*)d_in[18], (const float*)d_in[19],
        out);
}

// Round 13
// 734.845 us; speedup vs baseline: 1.4317x; 1.4317x over previous
//
#include <hip/hip_runtime.h>

#define EPSf 1e-5f
#define NPAD 72   // ci stride in window LDS: mult of 8 (16B-aligned b128), uniform banks

typedef __attribute__((ext_vector_type(8))) short short8;
typedef __attribute__((ext_vector_type(4))) float f32x4;

// Hand-rolled bf16 (round-to-nearest-even) for ws intermediates.
static __device__ __forceinline__ unsigned short f32_to_bf16(float f) {
    unsigned int u = __float_as_uint(f);
    unsigned int r = (u + 0x7FFFu + ((u >> 16) & 1u)) >> 16;
    return (unsigned short)r;
}
static __device__ __forceinline__ float bf16_to_f32(unsigned short h) {
    return __uint_as_float(((unsigned int)h) << 16);
}

// 3x3 conv (pad=1) + BN + ReLU via bf16 MFMA.
// Block 256 thr (4 waves), tile 16x8 px, all 64 c_out. grid (12,24,B).
// GEMM view: M=128px (8 M-tiles of 16), N=64cout (wave w owns 16), K=576 as
// 18 chunks of (tap=ky*3+kx, ci-half): each MFMA K=32 consecutive ci.
// A-frag: lane m=l&15=pxx, k-group l>>4: ds_read_b128 from win[row][col][ci].
// B-frag: preloaded VGPRs from global weights (147KB, L2-hot).
__global__ __launch_bounds__(256) void conv3x3_mfma(
    const float* __restrict__ in,    // [B,64,192,192] f32
    const float* __restrict__ wgt,   // [64,64,3,3]
    const float* __restrict__ bias,  // [64]
    const float* __restrict__ bn_g, const float* __restrict__ bn_be,
    const float* __restrict__ bn_m, const float* __restrict__ bn_v,
    unsigned short* __restrict__ out)  // [B,64,192,192] bf16 bits (workspace)
{
    __shared__ unsigned short win[10 * 18 * NPAD];   // 25.9 KB bf16 [row][col][ci]
    const int t  = threadIdx.x;
    const int x0 = blockIdx.x << 4, y0 = blockIdx.y << 3;
    const int b  = blockIdx.z;
    const float* inb = in + (size_t)b * 64 * 36864;

    // ---- stage 10x18 window, 64 ci, zero-padded, bf16, ci-innermost ----
    for (int i = t; i < 640; i += 256) {             // (ci,row) pairs
        int ci = i & 63, row = i >> 6;
        int gy = y0 - 1 + row;
        bool rowok = (gy >= 0 && gy < 192);
        const float* src = inb + (size_t)ci * 36864 + gy * 192 + (x0 - 1);
#pragma unroll
        for (int c = 0; c < 18; ++c) {
            int gx = x0 - 1 + c;
            float v = (rowok && gx >= 0 && gx < 192) ? src[c] : 0.f;
            win[(row * 18 + c) * NPAD + ci] = f32_to_bf16(v);
        }
    }

    // ---- B-fragment preload (weights -> 72 VGPRs) ----
    const int wv = t >> 6, l = t & 63;
    const int n  = l & 15, kg = l >> 4;              // kg 0..3
    const int cout = wv * 16 + n;
    short8 bfrag[18];
#pragma unroll
    for (int kc = 0; kc < 18; ++kc) {
        int cih = kc & 1, tap = kc >> 1;             // tap = ky*3+kx
        short8 v;
#pragma unroll
        for (int e = 0; e < 8; ++e) {
            int ci = cih * 32 + kg * 8 + e;
            float w = wgt[((size_t)cout * 64 + ci) * 9 + tap];
            ((unsigned short*)&v)[e] = f32_to_bf16(w);
        }
        bfrag[kc] = v;
    }

    // per-lane BN constants (lane's cout fixed)
    const float inv = bn_g[cout] / sqrtf(bn_v[cout] + EPSf);
    const float sh  = (bias[cout] - bn_m[cout]) * inv + bn_be[cout];

    f32x4 acc[8];
#pragma unroll
    for (int mt = 0; mt < 8; ++mt) acc[mt] = (f32x4){0.f, 0.f, 0.f, 0.f};

    __syncthreads();

    // ---- main loop: 18 K-chunks x 8 M-tiles, no barriers (win read-only) ----
#pragma unroll
    for (int kc = 0; kc < 18; ++kc) {
        int cih = kc & 1, tap = kc >> 1;
        int ky = tap / 3, kx = tap - ky * 3;
        const int cbase = cih * 32 + kg * 8;
        const int col = n + kx;                      // m = pxx = l&15 = n
#pragma unroll
        for (int mt = 0; mt < 8; ++mt) {
            const unsigned short* ap = &win[((mt + ky) * 18 + col) * NPAD + cbase];
            short8 a = *(const short8*)ap;           // ds_read_b128, 16B-aligned
            acc[mt] = __builtin_amdgcn_mfma_f32_16x16x32_bf16(a, bfrag[kc], acc[mt], 0, 0, 0);
        }
    }

    // ---- epilogue: BN+ReLU, store bf16. D: n=l&15 (cout), m=(l>>4)*4+r (pxx) ----
    const size_t ob = (size_t)b * 64 * 36864 + (size_t)cout * 36864;
#pragma unroll
    for (int mt = 0; mt < 8; ++mt) {
#pragma unroll
        for (int r = 0; r < 4; ++r) {
            int pxx = kg * 4 + r;
            float v = fmaf(acc[mt][r], inv, sh);
            out[ob + (size_t)(y0 + mt) * 192 + x0 + pxx] = f32_to_bf16(v > 0.f ? v : 0.f);
        }
    }
}

// Fused corr + 1x1 conv — EXACT round-9 version (measured 580us, known-good).
// corr channel = dx*9+dy, value = 0.125 * sum_c f1[c,y,x] * f2[c, y+dy-4, x+dx-4]
// grid = (12, 24, B), block = 128. OUTPUT IS FLOAT32.
__global__ __launch_bounds__(128) void corr_conv1x1_bn_relu(
    const unsigned short* __restrict__ f1, const unsigned short* __restrict__ f2,
    const float* __restrict__ qw,    // [64][145]
    const float* __restrict__ qb,
    const float* __restrict__ qg, const float* __restrict__ qbe,
    const float* __restrict__ qm, const float* __restrict__ qv,
    float* __restrict__ out)         // [B,64,192,192] f32
{
    __shared__ float sf2[3072];      // 8 ch x 16 rows x 24 cols
    const int t  = threadIdx.x;
    const int tx = t & 15, ty = t >> 4;
    const int x0 = blockIdx.x << 4, y0 = blockIdx.y << 3;
    const int b = blockIdx.z;
    const int x = x0 + tx, y = y0 + ty;
    const unsigned short* f1b = f1 + (size_t)b * 64 * 36864;
    const unsigned short* f2b = f2 + (size_t)b * 64 * 36864;

    float corr[81];
#pragma unroll
    for (int i = 0; i < 81; ++i) corr[i] = 0.f;

    for (int c0 = 0; c0 < 64; c0 += 8) {
#pragma unroll
        for (int k = 0; k < 24; ++k) {
            int i = t + (k << 7);
            int cc = i / 384; int rem = i - cc * 384;
            int r = rem / 24; int col = rem - r * 24;
            int gy = y0 - 4 + r, gx = x0 - 4 + col;
            float vv = 0.f;
            if (gy >= 0 && gy < 192 && gx >= 0 && gx < 192)
                vv = bf16_to_f32(f2b[(size_t)(c0 + cc) * 36864 + gy * 192 + gx]);
            sf2[i] = vv;
        }
        __syncthreads();

#pragma unroll
        for (int cc = 0; cc < 8; ++cc) {
            float f1v = bf16_to_f32(f1b[(size_t)(c0 + cc) * 36864 + y * 192 + x]);
            const float* sp = &sf2[cc * 384 + ty * 24 + tx];
#pragma unroll
            for (int dy = 0; dy < 9; ++dy)
#pragma unroll
                for (int dx = 0; dx < 9; ++dx)
                    corr[dx * 9 + dy] = fmaf(f1v, sp[dy * 24 + dx], corr[dx * 9 + dy]);
        }
        __syncthreads();
    }

#pragma unroll
    for (int d = 0; d < 81; ++d) corr[d] *= 0.125f;   // 1/sqrt(64)

    float f1r[64];
#pragma unroll
    for (int c = 0; c < 64; ++c)
        f1r[c] = bf16_to_f32(f1b[(size_t)c * 36864 + y * 192 + x]);

    size_t ob = (size_t)b * 64 * 36864 + (size_t)y * 192 + x;
    for (int co = 0; co < 64; ++co) {
        const float* wp = qw + co * 145;
        float a0 = 0.f, a1 = 0.f, a2 = 0.f, a3 = 0.f;
#pragma unroll
        for (int d = 0; d < 80; d += 4) {
            a0 = fmaf(wp[d + 0], corr[d + 0], a0);
            a1 = fmaf(wp[d + 1], corr[d + 1], a1);
            a2 = fmaf(wp[d + 2], corr[d + 2], a2);
            a3 = fmaf(wp[d + 3], corr[d + 3], a3);
        }
        a0 = fmaf(wp[80], corr[80], a0);
#pragma unroll
        for (int c = 0; c < 64; c += 4) {
            a0 = fmaf(wp[81 + c + 0], f1r[c + 0], a0);
            a1 = fmaf(wp[81 + c + 1], f1r[c + 1], a1);
            a2 = fmaf(wp[81 + c + 2], f1r[c + 2], a2);
            a3 = fmaf(wp[81 + c + 3], f1r[c + 3], a3);
        }
        float acc = (a0 + a1) + (a2 + a3);
        float inv = qg[co] / sqrtf(qv[co] + EPSf);
        float sh  = (qb[co] - qm[co]) * inv + qbe[co];
        float r = fmaf(acc, inv, sh);
        out[ob + (size_t)co * 36864] = (r > 0.f ? r : 0.f);
    }
}

extern "C" void kernel_launch(void* const* d_in, const int* in_sizes, int n_in,
                              void* d_out, int out_size, void* d_ws, size_t ws_size,
                              hipStream_t stream) {
    float* out = (float*)d_out;   // reference output dtype is float32

    // ws: f1 | f2, each 4*64*192*192 bf16 = 18.87 MB (total 37.75 MB)
    unsigned short* f1 = (unsigned short*)d_ws;
    unsigned short* f2 = f1 + (size_t)4 * 64 * 36864;

    dim3 cgrid(12, 24, 4);
    conv3x3_mfma<<<cgrid, 256, 0, stream>>>(
        (const float*)d_in[0], (const float*)d_in[2], (const float*)d_in[3],
        (const float*)d_in[4], (const float*)d_in[5], (const float*)d_in[6],
        (const float*)d_in[7], f1);
    conv3x3_mfma<<<cgrid, 256, 0, stream>>>(
        (const float*)d_in[1], (const float*)d_in[8], (const float*)d_in[9],
        (const float*)d_in[10], (const float*)d_in[11], (const float*)d_in[12],
        (const float*)d_in[13], f2);

    dim3 ggrid(12, 24, 4);
    corr_conv1x1_bn_relu<<<ggrid, 128, 0, stream>>>(
        f1, f2,
        (const float*)d_in[14], (const float*)d_in[15], (const float*)d_in[16],
        (const float*)d_in[17], (const float*)d_in[18], (const float*)d_in[19],
        out);
}

// Round 15
// 552.402 us; speedup vs baseline: 1.9046x; 1.3303x over previous
//
#include <hip/hip_runtime.h>

#define EPSf 1e-5f
#define NPAD 72   // ci stride in LDS: mult of 8 (16B-aligned b128), 2-way-free banks

typedef __attribute__((ext_vector_type(8))) short short8;
typedef __attribute__((ext_vector_type(4))) float f32x4;

static __device__ __forceinline__ unsigned short f32_to_bf16(float f) {
    unsigned int u = __float_as_uint(f);
    unsigned int r = (u + 0x7FFFu + ((u >> 16) & 1u)) >> 16;
    return (unsigned short)r;
}
static __device__ __forceinline__ float bf16_to_f32(unsigned short h) {
    return __uint_as_float(((unsigned int)h) << 16);
}

// 3x3 conv (pad=1) + BN + ReLU via bf16 MFMA. Round-13-validated core;
// channel-last epilogue [B][y][x][c] (r14).
__global__ __launch_bounds__(256) void conv3x3_mfma(
    const float* __restrict__ in,    // [B,64,192,192] f32
    const float* __restrict__ wgt,   // [64,64,3,3]
    const float* __restrict__ bias,  // [64]
    const float* __restrict__ bn_g, const float* __restrict__ bn_be,
    const float* __restrict__ bn_m, const float* __restrict__ bn_v,
    unsigned short* __restrict__ out)  // [B,192,192,64] bf16 bits (workspace)
{
    __shared__ unsigned short win[10 * 18 * NPAD];   // 25.9 KB bf16 [row][col][ci]
    const int t  = threadIdx.x;
    const int x0 = blockIdx.x << 4, y0 = blockIdx.y << 3;
    const int b  = blockIdx.z;
    const float* inb = in + (size_t)b * 64 * 36864;

    for (int i = t; i < 640; i += 256) {             // (ci,row) pairs
        int ci = i & 63, row = i >> 6;
        int gy = y0 - 1 + row;
        bool rowok = (gy >= 0 && gy < 192);
        const float* src = inb + (size_t)ci * 36864 + gy * 192 + (x0 - 1);
#pragma unroll
        for (int c = 0; c < 18; ++c) {
            int gx = x0 - 1 + c;
            float v = (rowok && gx >= 0 && gx < 192) ? src[c] : 0.f;
            win[(row * 18 + c) * NPAD + ci] = f32_to_bf16(v);
        }
    }

    const int wv = t >> 6, l = t & 63;
    const int n  = l & 15, kg = l >> 4;
    const int cout = wv * 16 + n;
    short8 bfrag[18];
#pragma unroll
    for (int kc = 0; kc < 18; ++kc) {
        int cih = kc & 1, tap = kc >> 1;
        short8 v;
#pragma unroll
        for (int e = 0; e < 8; ++e) {
            int ci = cih * 32 + kg * 8 + e;
            float w = wgt[((size_t)cout * 64 + ci) * 9 + tap];
            ((unsigned short*)&v)[e] = f32_to_bf16(w);
        }
        bfrag[kc] = v;
    }

    const float inv = bn_g[cout] / sqrtf(bn_v[cout] + EPSf);
    const float sh  = (bias[cout] - bn_m[cout]) * inv + bn_be[cout];

    f32x4 acc[8];
#pragma unroll
    for (int mt = 0; mt < 8; ++mt) acc[mt] = (f32x4){0.f, 0.f, 0.f, 0.f};

    __syncthreads();

#pragma unroll
    for (int kc = 0; kc < 18; ++kc) {
        int cih = kc & 1, tap = kc >> 1;
        int ky = tap / 3, kx = tap - ky * 3;
        const int cbase = cih * 32 + kg * 8;
        const int col = n + kx;
#pragma unroll
        for (int mt = 0; mt < 8; ++mt) {
            const unsigned short* ap = &win[((mt + ky) * 18 + col) * NPAD + cbase];
            short8 a = *(const short8*)ap;
            acc[mt] = __builtin_amdgcn_mfma_f32_16x16x32_bf16(a, bfrag[kc], acc[mt], 0, 0, 0);
        }
    }

    const size_t pbase = (size_t)b * 36864;
#pragma unroll
    for (int mt = 0; mt < 8; ++mt) {
#pragma unroll
        for (int r = 0; r < 4; ++r) {
            int pxx = kg * 4 + r;
            float v = fmaf(acc[mt][r], inv, sh);
            out[(pbase + (size_t)(y0 + mt) * 192 + x0 + pxx) * 64 + cout] =
                f32_to_bf16(v > 0.f ? v : 0.f);
        }
    }
}

// Corr via band-GEMM1 + scatter (r14 machinery, under test) + SCALAR 1x1 from
// cbuf (correct-by-construction r9 pattern). Bisects the r14 failure:
// PASS => GEMM2 was the bug. FAIL => staging/GEMM1/scatter.
// grid (12, 48, B), block 256 (4 waves), tile 16x4 px.
__global__ __launch_bounds__(256) void corr_band_mfma(
    const unsigned short* __restrict__ f1, const unsigned short* __restrict__ f2,
    const float* __restrict__ qw,    // [64][145]
    const float* __restrict__ qb,
    const float* __restrict__ qg, const float* __restrict__ qbe,
    const float* __restrict__ qm, const float* __restrict__ qv,
    float* __restrict__ out)         // [B,64,192,192] f32
{
    __shared__ unsigned short smem[20736 + 9728 + 8];   // 59.5 KB
    unsigned short* f2w  = smem;            // [12r][24u][72c-pad]
    unsigned short* cbuf = smem + 20736;    // [64px][152]: corr[0..81), pad, f1[88..152)

    const int t  = threadIdx.x;
    const int x0 = blockIdx.x << 4, y0 = blockIdx.y << 2;
    const int b  = blockIdx.z;
    const int wv = t >> 6, l = t & 63;
    const int n15 = l & 15, kg = l >> 4, hi4 = kg << 2;
    const size_t pbase = (size_t)b * 36864;

    // ---- stage f2 window [12][24][64c] (zero-padded borders) ----
#pragma unroll
    for (int i = 0; i < 9; ++i) {
        int q = t + (i << 8);                 // 0..2303
        int r = q / 192, rem = q - r * 192;
        int u = rem >> 3, j = rem & 7;
        int gy = y0 - 4 + r, gx = x0 - 4 + u;
        short8 v = {0, 0, 0, 0, 0, 0, 0, 0};
        if (gy >= 0 && gy < 192 && gx >= 0 && gx < 192)
            v = *(const short8*)&f2[(pbase + (size_t)gy * 192 + gx) * 64 + j * 8];
        *(short8*)&f2w[(r * 24 + u) * NPAD + j * 8] = v;
    }
    // ---- stage f1 tile into cbuf[px][88..152) ----
#pragma unroll
    for (int i = 0; i < 2; ++i) {
        int q = t + (i << 8);                 // 0..511
        int px = q >> 3, j = q & 7;
        int gy = y0 + (px >> 4), gx = x0 + (px & 15);
        short8 v = *(const short8*)&f1[(pbase + (size_t)gy * 192 + gx) * 64 + j * 8];
        *(short8*)&cbuf[px * 152 + 88 + j * 8] = v;
    }
    if (t < 64) {
#pragma unroll
        for (int d = 81; d < 88; ++d) cbuf[t * 152 + d] = 0;
    }

    __syncthreads();

    // ---- GEMM1: wave wv handles y-row ty=wv ----
    const int ty = wv, tx = n15;
    short8 bfr0 = *(const short8*)&cbuf[(ty * 16 + n15) * 152 + 88 + kg * 8];
    short8 bfr1 = *(const short8*)&cbuf[(ty * 16 + n15) * 152 + 88 + 32 + kg * 8];
    f32x4 acc[14];
#pragma unroll
    for (int Mt = 0; Mt < 14; ++Mt) acc[Mt] = (f32x4){0.f, 0.f, 0.f, 0.f};
#pragma unroll
    for (int Mt = 0; Mt < 14; ++Mt) {
        int row = ty * 24 + Mt * 16 + n15;    // = (ty+bb)*24 + u
        short8 a0 = *(const short8*)&f2w[row * NPAD + kg * 8];
        short8 a1 = *(const short8*)&f2w[row * NPAD + 32 + kg * 8];
        acc[Mt] = __builtin_amdgcn_mfma_f32_16x16x32_bf16(a0, bfr0, acc[Mt], 0, 0, 0);
        acc[Mt] = __builtin_amdgcn_mfma_f32_16x16x32_bf16(a1, bfr1, acc[Mt], 0, 0, 0);
    }
    // scatter band diagonals: D row m = Mt*16 + hi4 + r, col = tx
    const int rowb = (ty * 16 + tx) * 152;
#pragma unroll
    for (int Mt = 0; Mt < 14; ++Mt) {
#pragma unroll
        for (int r = 0; r < 4; ++r) {
            int m  = Mt * 16 + hi4 + r;
            int bb = m / 24;
            int u  = m - bb * 24;
            int a  = u - tx;
            if (m < 216 && a >= 0 && a <= 8)
                cbuf[rowb + a * 9 + bb] = f32_to_bf16(acc[Mt][r] * 0.125f);
        }
    }
    __syncthreads();

    // ---- phase 2: SCALAR 1x1 (145->64) + BN + ReLU from cbuf ----
    // lane (wv, n15, kg): pixel px = wv*16+n15, couts kg*16..kg*16+15.
    const int px = wv * 16 + n15;
    const unsigned short* cb = &cbuf[px * 152];
    const int gy = y0 + (px >> 4), gx = x0 + (px & 15);
    const size_t ob = (size_t)b * 64 * 36864 + (size_t)gy * 192 + gx;
#pragma unroll 2
    for (int j = 0; j < 16; ++j) {
        int co = kg * 16 + j;
        const float* wp = qw + co * 145;
        float a0 = 0.f, a1 = 0.f, a2 = 0.f, a3 = 0.f;
#pragma unroll
        for (int d = 0; d < 80; d += 4) {
            a0 = fmaf(wp[d + 0], bf16_to_f32(cb[d + 0]), a0);
            a1 = fmaf(wp[d + 1], bf16_to_f32(cb[d + 1]), a1);
            a2 = fmaf(wp[d + 2], bf16_to_f32(cb[d + 2]), a2);
            a3 = fmaf(wp[d + 3], bf16_to_f32(cb[d + 3]), a3);
        }
        a0 = fmaf(wp[80], bf16_to_f32(cb[80]), a0);
#pragma unroll
        for (int c = 0; c < 64; c += 4) {
            a0 = fmaf(wp[81 + c + 0], bf16_to_f32(cb[88 + c + 0]), a0);
            a1 = fmaf(wp[81 + c + 1], bf16_to_f32(cb[88 + c + 1]), a1);
            a2 = fmaf(wp[81 + c + 2], bf16_to_f32(cb[88 + c + 2]), a2);
            a3 = fmaf(wp[81 + c + 3], bf16_to_f32(cb[88 + c + 3]), a3);
        }
        float acc1 = (a0 + a1) + (a2 + a3);
        float inv = qg[co] / sqrtf(qv[co] + EPSf);
        float sh  = (qb[co] - qm[co]) * inv + qbe[co];
        float r = fmaf(acc1, inv, sh);
        out[ob + (size_t)co * 36864] = (r > 0.f ? r : 0.f);
    }
}

extern "C" void kernel_launch(void* const* d_in, const int* in_sizes, int n_in,
                              void* d_out, int out_size, void* d_ws, size_t ws_size,
                              hipStream_t stream) {
    float* out = (float*)d_out;   // reference output dtype is float32

    // ws: f1 | f2, each [4][192][192][64] bf16 (channel-last) = 18.87 MB
    unsigned short* f1 = (unsigned short*)d_ws;
    unsigned short* f2 = f1 + (size_t)4 * 64 * 36864;

    dim3 cgrid(12, 24, 4);
    conv3x3_mfma<<<cgrid, 256, 0, stream>>>(
        (const float*)d_in[0], (const float*)d_in[2], (const float*)d_in[3],
        (const float*)d_in[4], (const float*)d_in[5], (const float*)d_in[6],
        (const float*)d_in[7], f1);
    conv3x3_mfma<<<cgrid, 256, 0, stream>>>(
        (const float*)d_in[1], (const float*)d_in[8], (const float*)d_in[9],
        (const float*)d_in[10], (const float*)d_in[11], (const float*)d_in[12],
        (const float*)d_in[13], f2);

    dim3 ggrid(12, 48, 4);
    corr_band_mfma<<<ggrid, 256, 0, stream>>>(
        f1, f2,
        (const float*)d_in[14], (const float*)d_in[15], (const float*)d_in[16],
        (const float*)d_in[17], (const float*)d_in[18], (const float*)d_in[19],
        out);
}

// Round 16
// 224.382 us; speedup vs baseline: 4.6889x; 2.4619x over previous
//
#include <hip/hip_runtime.h>

#define EPSf 1e-5f
#define NPAD 72     // f2w ci stride: 16B-aligned b128, 2-way-free banks
#define CSTR 168    // cbuf row stride: 336B, 16B-aligned, period-8 bank spread

typedef __attribute__((ext_vector_type(8))) short short8;
typedef __attribute__((ext_vector_type(4))) float f32x4;

static __device__ __forceinline__ unsigned short f32_to_bf16(float f) {
    unsigned int u = __float_as_uint(f);
    unsigned int r = (u + 0x7FFFu + ((u >> 16) & 1u)) >> 16;
    return (unsigned short)r;
}
static __device__ __forceinline__ float bf16_to_f32(unsigned short h) {
    return __uint_as_float(((unsigned int)h) << 16);
}

// 3x3 conv (pad=1) + BN + ReLU via bf16 MFMA. Validated r13-r15; channel-last ws.
__global__ __launch_bounds__(256) void conv3x3_mfma(
    const float* __restrict__ in,    // [B,64,192,192] f32
    const float* __restrict__ wgt,   // [64,64,3,3]
    const float* __restrict__ bias,  // [64]
    const float* __restrict__ bn_g, const float* __restrict__ bn_be,
    const float* __restrict__ bn_m, const float* __restrict__ bn_v,
    unsigned short* __restrict__ out)  // [B,192,192,64] bf16 bits (workspace)
{
    __shared__ unsigned short win[10 * 18 * NPAD];   // 25.9 KB bf16 [row][col][ci]
    const int t  = threadIdx.x;
    const int x0 = blockIdx.x << 4, y0 = blockIdx.y << 3;
    const int b  = blockIdx.z;
    const float* inb = in + (size_t)b * 64 * 36864;

    for (int i = t; i < 640; i += 256) {             // (ci,row) pairs
        int ci = i & 63, row = i >> 6;
        int gy = y0 - 1 + row;
        bool rowok = (gy >= 0 && gy < 192);
        const float* src = inb + (size_t)ci * 36864 + gy * 192 + (x0 - 1);
#pragma unroll
        for (int c = 0; c < 18; ++c) {
            int gx = x0 - 1 + c;
            float v = (rowok && gx >= 0 && gx < 192) ? src[c] : 0.f;
            win[(row * 18 + c) * NPAD + ci] = f32_to_bf16(v);
        }
    }

    const int wv = t >> 6, l = t & 63;
    const int n  = l & 15, kg = l >> 4;
    const int cout = wv * 16 + n;
    short8 bfrag[18];
#pragma unroll
    for (int kc = 0; kc < 18; ++kc) {
        int cih = kc & 1, tap = kc >> 1;
        short8 v;
#pragma unroll
        for (int e = 0; e < 8; ++e) {
            int ci = cih * 32 + kg * 8 + e;
            float w = wgt[((size_t)cout * 64 + ci) * 9 + tap];
            ((unsigned short*)&v)[e] = f32_to_bf16(w);
        }
        bfrag[kc] = v;
    }

    const float inv = bn_g[cout] / sqrtf(bn_v[cout] + EPSf);
    const float sh  = (bias[cout] - bn_m[cout]) * inv + bn_be[cout];

    f32x4 acc[8];
#pragma unroll
    for (int mt = 0; mt < 8; ++mt) acc[mt] = (f32x4){0.f, 0.f, 0.f, 0.f};

    __syncthreads();

#pragma unroll
    for (int kc = 0; kc < 18; ++kc) {
        int cih = kc & 1, tap = kc >> 1;
        int ky = tap / 3, kx = tap - ky * 3;
        const int cbase = cih * 32 + kg * 8;
        const int col = n + kx;
#pragma unroll
        for (int mt = 0; mt < 8; ++mt) {
            const unsigned short* ap = &win[((mt + ky) * 18 + col) * NPAD + cbase];
            short8 a = *(const short8*)ap;
            acc[mt] = __builtin_amdgcn_mfma_f32_16x16x32_bf16(a, bfrag[kc], acc[mt], 0, 0, 0);
        }
    }

    const size_t pbase = (size_t)b * 36864;
#pragma unroll
    for (int mt = 0; mt < 8; ++mt) {
#pragma unroll
        for (int r = 0; r < 4; ++r) {
            int pxx = kg * 4 + r;
            float v = fmaf(acc[mt][r], inv, sh);
            out[(pbase + (size_t)(y0 + mt) * 192 + x0 + pxx) * 64 + cout] =
                f32_to_bf16(v > 0.f ? v : 0.f);
        }
    }
}

// Fused corr(R=4) + 1x1 conv, full MFMA. Validated pieces: staging+GEMM1+scatter
// (r15). GEMM2 re-enabled with ALL reads defined: cbuf stride 168, zeros at
// [81,88) and [152,168) so every 0-weight K-slot multiplies true zeros.
// grid (12, 48, B), block 256 (4 waves), tile 16x4 px.
__global__ __launch_bounds__(256) void corr_conv1x1_mfma(
    const unsigned short* __restrict__ f1, const unsigned short* __restrict__ f2,
    const float* __restrict__ qw,    // [64][145]
    const float* __restrict__ qb,
    const float* __restrict__ qg, const float* __restrict__ qbe,
    const float* __restrict__ qm, const float* __restrict__ qv,
    float* __restrict__ out)         // [B,64,192,192] f32
{
    __shared__ unsigned short smem[20736 + 64 * CSTR];   // 62976 B
    unsigned short* f2w  = smem;            // [12r][24u][72c-pad]
    unsigned short* cbuf = smem + 20736;    // [64px][168]: corr[0..81) | 0 | f1[88..152) | 0

    const int t  = threadIdx.x;
    const int x0 = blockIdx.x << 4, y0 = blockIdx.y << 2;
    const int b  = blockIdx.z;
    const int wv = t >> 6, l = t & 63;
    const int n15 = l & 15, kg = l >> 4, hi4 = kg << 2;
    const size_t pbase = (size_t)b * 36864;

    // ---- stage f2 window [12][24][64c] (zero-padded borders) ----
#pragma unroll
    for (int i = 0; i < 9; ++i) {
        int q = t + (i << 8);                 // 0..2303
        int r = q / 192, rem = q - r * 192;
        int u = rem >> 3, j = rem & 7;
        int gy = y0 - 4 + r, gx = x0 - 4 + u;
        short8 v = {0, 0, 0, 0, 0, 0, 0, 0};
        if (gy >= 0 && gy < 192 && gx >= 0 && gx < 192)
            v = *(const short8*)&f2[(pbase + (size_t)gy * 192 + gx) * 64 + j * 8];
        *(short8*)&f2w[(r * 24 + u) * NPAD + j * 8] = v;
    }
    // ---- stage f1 tile into cbuf[px][88..152) ----
#pragma unroll
    for (int i = 0; i < 2; ++i) {
        int q = t + (i << 8);                 // 0..511
        int px = q >> 3, j = q & 7;
        int gy = y0 + (px >> 4), gx = x0 + (px & 15);
        short8 v = *(const short8*)&f1[(pbase + (size_t)gy * 192 + gx) * 64 + j * 8];
        *(short8*)&cbuf[px * CSTR + 88 + j * 8] = v;
    }
    // ---- zero the K-gaps so zero-weight slots multiply true zeros ----
    if (t < 64) {
#pragma unroll
        for (int d = 81; d < 88; ++d)  cbuf[t * CSTR + d] = 0;
#pragma unroll
        for (int d = 152; d < 168; ++d) cbuf[t * CSTR + d] = 0;
    }

    // ---- W2 A-fragments (K=160; k<81 corr wgt, [88,152) f1 wgt, else 0) ----
    const int cout_a = wv * 16 + n15;
    short8 w2[5];
#pragma unroll
    for (int s = 0; s < 5; ++s) {
        short8 v;
#pragma unroll
        for (int e = 0; e < 8; ++e) {
            int k = s * 32 + kg * 8 + e;
            float w = 0.f;
            if (k < 81)                  w = qw[cout_a * 145 + k];
            else if (k >= 88 && k < 152) w = qw[cout_a * 145 + k - 7];
            ((unsigned short*)&v)[e] = f32_to_bf16(w);
        }
        w2[s] = v;
    }
    float inv4[4], sh4[4];
#pragma unroll
    for (int r = 0; r < 4; ++r) {
        int c = wv * 16 + hi4 + r;
        inv4[r] = qg[c] / sqrtf(qv[c] + EPSf);
        sh4[r]  = (qb[c] - qm[c]) * inv4[r] + qbe[c];
    }

    __syncthreads();

    // ---- GEMM1 + fused scatter: wave wv = y-row ty ----
    // G[m=bb*24+u][tx] = sum_c f2w[ty+bb][u][c] * f1[ty*16+tx][c]
    // corr[a*9+bb][px=ty*16+tx] = G[bb*24+tx+a][tx] * 0.125
    const int ty = wv, tx = n15;
    short8 bfr0 = *(const short8*)&cbuf[(ty * 16 + n15) * CSTR + 88 + kg * 8];
    short8 bfr1 = *(const short8*)&cbuf[(ty * 16 + n15) * CSTR + 120 + kg * 8];
    const int rowb = (ty * 16 + tx) * CSTR;
#pragma unroll
    for (int Mt = 0; Mt < 14; ++Mt) {
        int row = ty * 24 + Mt * 16 + n15;    // = (ty+bb)*24 + u
        short8 a0 = *(const short8*)&f2w[row * NPAD + kg * 8];
        short8 a1 = *(const short8*)&f2w[row * NPAD + 32 + kg * 8];
        f32x4 acc = (f32x4){0.f, 0.f, 0.f, 0.f};
        acc = __builtin_amdgcn_mfma_f32_16x16x32_bf16(a0, bfr0, acc, 0, 0, 0);
        acc = __builtin_amdgcn_mfma_f32_16x16x32_bf16(a1, bfr1, acc, 0, 0, 0);
#pragma unroll
        for (int r = 0; r < 4; ++r) {
            int m  = Mt * 16 + hi4 + r;       // D row
            int bb = m / 24;
            int u  = m - bb * 24;
            int a  = u - tx;
            if (m < 216 && a >= 0 && a <= 8)
                cbuf[rowb + a * 9 + bb] = f32_to_bf16(acc[r] * 0.125f);
        }
    }
    __syncthreads();

    // ---- GEMM2: M=64 cout (wave=M-tile), N=64 px (4 N-tiles), K=160 ----
    f32x4 acc2[4];
#pragma unroll
    for (int Nt = 0; Nt < 4; ++Nt) {
        acc2[Nt] = (f32x4){0.f, 0.f, 0.f, 0.f};
#pragma unroll
        for (int s = 0; s < 5; ++s) {
            short8 bfr = *(const short8*)&cbuf[(Nt * 16 + n15) * CSTR + s * 32 + kg * 8];
            acc2[Nt] = __builtin_amdgcn_mfma_f32_16x16x32_bf16(w2[s], bfr, acc2[Nt], 0, 0, 0);
        }
    }
    // epilogue: D row = cout-in-tile (hi4+r), col = px-in-tile (n15). f32 store.
#pragma unroll
    for (int Nt = 0; Nt < 4; ++Nt) {
        int gy = y0 + Nt, gx = x0 + n15;
#pragma unroll
        for (int r = 0; r < 4; ++r) {
            int c = wv * 16 + hi4 + r;
            float v = fmaf(acc2[Nt][r], inv4[r], sh4[r]);
            out[((size_t)(b * 64 + c)) * 36864 + (size_t)gy * 192 + gx] = v > 0.f ? v : 0.f;
        }
    }
}

extern "C" void kernel_launch(void* const* d_in, const int* in_sizes, int n_in,
                              void* d_out, int out_size, void* d_ws, size_t ws_size,
                              hipStream_t stream) {
    float* out = (float*)d_out;   // reference output dtype is float32

    // ws: f1 | f2, each [4][192][192][64] bf16 (channel-last) = 18.87 MB
    unsigned short* f1 = (unsigned short*)d_ws;
    unsigned short* f2 = f1 + (size_t)4 * 64 * 36864;

    dim3 cgrid(12, 24, 4);
    conv3x3_mfma<<<cgrid, 256, 0, stream>>>(
        (const float*)d_in[0], (const float*)d_in[2], (const float*)d_in[3],
        (const float*)d_in[4], (const float*)d_in[5], (const float*)d_in[6],
        (const float*)d_in[7], f1);
    conv3x3_mfma<<<cgrid, 256, 0, stream>>>(
        (const float*)d_in[1], (const float*)d_in[8], (const float*)d_in[9],
        (const float*)d_in[10], (const float*)d_in[11], (const float*)d_in[12],
        (const float*)d_in[13], f2);

    dim3 ggrid(12, 48, 4);
    corr_conv1x1_mfma<<<ggrid, 256, 0, stream>>>(
        f1, f2,
        (const float*)d_in[14], (const float*)d_in[15], (const float*)d_in[16],
        (const float*)d_in[17], (const float*)d_in[18], (const float*)d_in[19],
        out);
}

// Round 17
// 200.682 us; speedup vs baseline: 5.2427x; 1.1181x over previous
//
#include <hip/hip_runtime.h>

#define EPSf 1e-5f
#define NPAD 72     // f2w/win ci stride: 16B-aligned b128, 2-way-free banks
#define CSTR 168    // cbuf row stride: 336B, 16B-aligned, period-8 bank spread

typedef __attribute__((ext_vector_type(8))) short short8;
typedef __attribute__((ext_vector_type(4))) float f32x4;

static __device__ __forceinline__ unsigned short f32_to_bf16(float f) {
    unsigned int u = __float_as_uint(f);
    unsigned int r = (u + 0x7FFFu + ((u >> 16) & 1u)) >> 16;
    return (unsigned short)r;
}
static __device__ __forceinline__ float bf16_to_f32(unsigned short h) {
    return __uint_as_float(((unsigned int)h) << 16);
}

// Reorder conv weights into MFMA-fragment order, bf16:
// frag[((wv*18+kc)*64+l)*8+e] = bf16(w[cout=wv*16+(l&15)][ci=(kc&1)*32+(l>>4)*8+e][tap=kc>>1])
// so each wave loads bfrag[kc] as one coalesced 16B/lane read. grid 2 (K,Q), block 256.
__global__ __launch_bounds__(256) void prep_wfrag(
    const float* __restrict__ wK, const float* __restrict__ wQ,
    unsigned short* __restrict__ fK, unsigned short* __restrict__ fQ)
{
    const float* src = (blockIdx.x == 0) ? wK : wQ;
    unsigned short* dst = (blockIdx.x == 0) ? fK : fQ;
    const int t = threadIdx.x;
#pragma unroll
    for (int it = 0; it < 18; ++it) {
        int s = t + it * 256;                 // 0..4607
        int l = s & 63, rest = s >> 6;
        int kc = rest % 18, wv = rest / 18;
        int n = l & 15, kg = l >> 4;
        int cout = wv * 16 + n, cih = kc & 1, tap = kc >> 1;
        short8 v;
#pragma unroll
        for (int e = 0; e < 8; ++e) {
            int ci = cih * 32 + kg * 8 + e;
            ((unsigned short*)&v)[e] = f32_to_bf16(src[(size_t)cout * 576 + ci * 9 + tap]);
        }
        *(short8*)&dst[(size_t)s * 8] = v;
    }
}

// 3x3 conv (pad=1) + BN + ReLU via bf16 MFMA. r13-r16-validated core; weight
// fragments now read coalesced from prepacked array (was 144 scalar loads).
__global__ __launch_bounds__(256) void conv3x3_mfma(
    const float* __restrict__ in,    // [B,64,192,192] f32
    const unsigned short* __restrict__ wfrag,  // [4][18][64][8] bf16 fragment-ordered
    const float* __restrict__ bias,  // [64]
    const float* __restrict__ bn_g, const float* __restrict__ bn_be,
    const float* __restrict__ bn_m, const float* __restrict__ bn_v,
    unsigned short* __restrict__ out)  // [B,192,192,64] bf16 bits (workspace)
{
    __shared__ unsigned short win[10 * 18 * NPAD];   // 25.9 KB bf16 [row][col][ci]
    const int t  = threadIdx.x;
    const int x0 = blockIdx.x << 4, y0 = blockIdx.y << 3;
    const int b  = blockIdx.z;
    const float* inb = in + (size_t)b * 64 * 36864;

    for (int i = t; i < 640; i += 256) {             // (ci,row) pairs
        int ci = i & 63, row = i >> 6;
        int gy = y0 - 1 + row;
        bool rowok = (gy >= 0 && gy < 192);
        const float* src = inb + (size_t)ci * 36864 + gy * 192 + (x0 - 1);
#pragma unroll
        for (int c = 0; c < 18; ++c) {
            int gx = x0 - 1 + c;
            float v = (rowok && gx >= 0 && gx < 192) ? src[c] : 0.f;
            win[(row * 18 + c) * NPAD + ci] = f32_to_bf16(v);
        }
    }

    const int wv = t >> 6, l = t & 63;
    const int n  = l & 15, kg = l >> 4;
    const int cout = wv * 16 + n;

    // coalesced fragment loads: addr ((wv*18+kc)*64+l)*8
    short8 bfrag[18];
    const unsigned short* wf = wfrag + (size_t)wv * 9216 + l * 8;
#pragma unroll
    for (int kc = 0; kc < 18; ++kc)
        bfrag[kc] = *(const short8*)&wf[kc * 512];

    const float inv = bn_g[cout] / sqrtf(bn_v[cout] + EPSf);
    const float sh  = (bias[cout] - bn_m[cout]) * inv + bn_be[cout];

    f32x4 acc[8];
#pragma unroll
    for (int mt = 0; mt < 8; ++mt) acc[mt] = (f32x4){0.f, 0.f, 0.f, 0.f};

    __syncthreads();

#pragma unroll
    for (int kc = 0; kc < 18; ++kc) {
        int cih = kc & 1, tap = kc >> 1;
        int ky = tap / 3, kx = tap - ky * 3;
        const int cbase = cih * 32 + kg * 8;
        const int col = n + kx;
#pragma unroll
        for (int mt = 0; mt < 8; ++mt) {
            const unsigned short* ap = &win[((mt + ky) * 18 + col) * NPAD + cbase];
            short8 a = *(const short8*)ap;
            acc[mt] = __builtin_amdgcn_mfma_f32_16x16x32_bf16(a, bfrag[kc], acc[mt], 0, 0, 0);
        }
    }

    const size_t pbase = (size_t)b * 36864;
#pragma unroll
    for (int mt = 0; mt < 8; ++mt) {
#pragma unroll
        for (int r = 0; r < 4; ++r) {
            int pxx = kg * 4 + r;
            float v = fmaf(acc[mt][r], inv, sh);
            out[(pbase + (size_t)(y0 + mt) * 192 + x0 + pxx) * 64 + cout] =
                f32_to_bf16(v > 0.f ? v : 0.f);
        }
    }
}

// Fused corr(R=4) + 1x1 conv, full MFMA — EXACT round-16 version (validated).
__global__ __launch_bounds__(256) void corr_conv1x1_mfma(
    const unsigned short* __restrict__ f1, const unsigned short* __restrict__ f2,
    const float* __restrict__ qw,    // [64][145]
    const float* __restrict__ qb,
    const float* __restrict__ qg, const float* __restrict__ qbe,
    const float* __restrict__ qm, const float* __restrict__ qv,
    float* __restrict__ out)         // [B,64,192,192] f32
{
    __shared__ unsigned short smem[20736 + 64 * CSTR];   // 62976 B
    unsigned short* f2w  = smem;            // [12r][24u][72c-pad]
    unsigned short* cbuf = smem + 20736;    // [64px][168]: corr[0..81) | 0 | f1[88..152) | 0

    const int t  = threadIdx.x;
    const int x0 = blockIdx.x << 4, y0 = blockIdx.y << 2;
    const int b  = blockIdx.z;
    const int wv = t >> 6, l = t & 63;
    const int n15 = l & 15, kg = l >> 4, hi4 = kg << 2;
    const size_t pbase = (size_t)b * 36864;

#pragma unroll
    for (int i = 0; i < 9; ++i) {
        int q = t + (i << 8);                 // 0..2303
        int r = q / 192, rem = q - r * 192;
        int u = rem >> 3, j = rem & 7;
        int gy = y0 - 4 + r, gx = x0 - 4 + u;
        short8 v = {0, 0, 0, 0, 0, 0, 0, 0};
        if (gy >= 0 && gy < 192 && gx >= 0 && gx < 192)
            v = *(const short8*)&f2[(pbase + (size_t)gy * 192 + gx) * 64 + j * 8];
        *(short8*)&f2w[(r * 24 + u) * NPAD + j * 8] = v;
    }
#pragma unroll
    for (int i = 0; i < 2; ++i) {
        int q = t + (i << 8);                 // 0..511
        int px = q >> 3, j = q & 7;
        int gy = y0 + (px >> 4), gx = x0 + (px & 15);
        short8 v = *(const short8*)&f1[(pbase + (size_t)gy * 192 + gx) * 64 + j * 8];
        *(short8*)&cbuf[px * CSTR + 88 + j * 8] = v;
    }
    if (t < 64) {
#pragma unroll
        for (int d = 81; d < 88; ++d)  cbuf[t * CSTR + d] = 0;
#pragma unroll
        for (int d = 152; d < 168; ++d) cbuf[t * CSTR + d] = 0;
    }

    const int cout_a = wv * 16 + n15;
    short8 w2[5];
#pragma unroll
    for (int s = 0; s < 5; ++s) {
        short8 v;
#pragma unroll
        for (int e = 0; e < 8; ++e) {
            int k = s * 32 + kg * 8 + e;
            float w = 0.f;
            if (k < 81)                  w = qw[cout_a * 145 + k];
            else if (k >= 88 && k < 152) w = qw[cout_a * 145 + k - 7];
            ((unsigned short*)&v)[e] = f32_to_bf16(w);
        }
        w2[s] = v;
    }
    float inv4[4], sh4[4];
#pragma unroll
    for (int r = 0; r < 4; ++r) {
        int c = wv * 16 + hi4 + r;
        inv4[r] = qg[c] / sqrtf(qv[c] + EPSf);
        sh4[r]  = (qb[c] - qm[c]) * inv4[r] + qbe[c];
    }

    __syncthreads();

    const int ty = wv, tx = n15;
    short8 bfr0 = *(const short8*)&cbuf[(ty * 16 + n15) * CSTR + 88 + kg * 8];
    short8 bfr1 = *(const short8*)&cbuf[(ty * 16 + n15) * CSTR + 120 + kg * 8];
    const int rowb = (ty * 16 + tx) * CSTR;
#pragma unroll
    for (int Mt = 0; Mt < 14; ++Mt) {
        int row = ty * 24 + Mt * 16 + n15;    // = (ty+bb)*24 + u
        short8 a0 = *(const short8*)&f2w[row * NPAD + kg * 8];
        short8 a1 = *(const short8*)&f2w[row * NPAD + 32 + kg * 8];
        f32x4 acc = (f32x4){0.f, 0.f, 0.f, 0.f};
        acc = __builtin_amdgcn_mfma_f32_16x16x32_bf16(a0, bfr0, acc, 0, 0, 0);
        acc = __builtin_amdgcn_mfma_f32_16x16x32_bf16(a1, bfr1, acc, 0, 0, 0);
#pragma unroll
        for (int r = 0; r < 4; ++r) {
            int m  = Mt * 16 + hi4 + r;       // D row
            int bb = m / 24;
            int u  = m - bb * 24;
            int a  = u - tx;
            if (m < 216 && a >= 0 && a <= 8)
                cbuf[rowb + a * 9 + bb] = f32_to_bf16(acc[r] * 0.125f);
        }
    }
    __syncthreads();

    f32x4 acc2[4];
#pragma unroll
    for (int Nt = 0; Nt < 4; ++Nt) {
        acc2[Nt] = (f32x4){0.f, 0.f, 0.f, 0.f};
#pragma unroll
        for (int s = 0; s < 5; ++s) {
            short8 bfr = *(const short8*)&cbuf[(Nt * 16 + n15) * CSTR + s * 32 + kg * 8];
            acc2[Nt] = __builtin_amdgcn_mfma_f32_16x16x32_bf16(w2[s], bfr, acc2[Nt], 0, 0, 0);
        }
    }
#pragma unroll
    for (int Nt = 0; Nt < 4; ++Nt) {
        int gy = y0 + Nt, gx = x0 + n15;
#pragma unroll
        for (int r = 0; r < 4; ++r) {
            int c = wv * 16 + hi4 + r;
            float v = fmaf(acc2[Nt][r], inv4[r], sh4[r]);
            out[((size_t)(b * 64 + c)) * 36864 + (size_t)gy * 192 + gx] = v > 0.f ? v : 0.f;
        }
    }
}

extern "C" void kernel_launch(void* const* d_in, const int* in_sizes, int n_in,
                              void* d_out, int out_size, void* d_ws, size_t ws_size,
                              hipStream_t stream) {
    float* out = (float*)d_out;   // reference output dtype is float32

    // ws: f1 | f2, each [4][192][192][64] bf16 (channel-last) = 18.87 MB
    unsigned short* f1 = (unsigned short*)d_ws;
    unsigned short* f2 = f1 + (size_t)4 * 64 * 36864;

    // Weight fragments live in the TAIL of d_out (147456 B, exactly fills it):
    // consumed by the convs, then corr overwrites all of d_out. No ws growth.
    unsigned short* wfK = (unsigned short*)d_out + 18800640;  // byte 37601280
    unsigned short* wfQ = wfK + 36864;                        // ends at 37748736

    prep_wfrag<<<dim3(2), 256, 0, stream>>>(
        (const float*)d_in[2], (const float*)d_in[8], wfK, wfQ);

    dim3 cgrid(12, 24, 4);
    conv3x3_mfma<<<cgrid, 256, 0, stream>>>(
        (const float*)d_in[0], wfK, (const float*)d_in[3],
        (const float*)d_in[4], (const float*)d_in[5], (const float*)d_in[6],
        (const float*)d_in[7], f1);
    conv3x3_mfma<<<cgrid, 256, 0, stream>>>(
        (const float*)d_in[1], wfQ, (const float*)d_in[9],
        (const float*)d_in[10], (const float*)d_in[11], (const float*)d_in[12],
        (const float*)d_in[13], f2);

    dim3 ggrid(12, 48, 4);
    corr_conv1x1_mfma<<<ggrid, 256, 0, stream>>>(
        f1, f2,
        (const float*)d_in[14], (const float*)d_in[15], (const float*)d_in[16],
        (const float*)d_in[17], (const float*)d_in[18], (const float*)d_in[19],
        out);
}

// Round 19
// 177.417 us; speedup vs baseline: 5.9301x; 1.1311x over previous
//
#include <hip/hip_runtime.h>

#define EPSf 1e-5f
#define NPAD 72     // f2w/win ci stride: 16B-aligned b128, 2-way-free banks
#define CSTR 168    // cbuf row stride: 336B, 16B-aligned, period-8 bank spread

typedef __attribute__((ext_vector_type(8))) short short8;
typedef __attribute__((ext_vector_type(4))) float f32x4;

static __device__ __forceinline__ unsigned short f32_to_bf16(float f) {
    unsigned int u = __float_as_uint(f);
    unsigned int r = (u + 0x7FFFu + ((u >> 16) & 1u)) >> 16;
    return (unsigned short)r;
}
static __device__ __forceinline__ float bf16_to_f32(unsigned short h) {
    return __uint_as_float(((unsigned int)h) << 16);
}

// Reorder conv weights into MFMA-fragment order (r17-validated). grid 2, block 256.
__global__ __launch_bounds__(256) void prep_wfrag(
    const float* __restrict__ wK, const float* __restrict__ wQ,
    unsigned short* __restrict__ fK, unsigned short* __restrict__ fQ)
{
    const float* src = (blockIdx.x == 0) ? wK : wQ;
    unsigned short* dst = (blockIdx.x == 0) ? fK : fQ;
    const int t = threadIdx.x;
#pragma unroll
    for (int it = 0; it < 18; ++it) {
        int s = t + it * 256;                 // 0..4607
        int l = s & 63, rest = s >> 6;
        int kc = rest % 18, wv = rest / 18;
        int n = l & 15, kg = l >> 4;
        int cout = wv * 16 + n, cih = kc & 1, tap = kc >> 1;
        short8 v;
#pragma unroll
        for (int e = 0; e < 8; ++e) {
            int ci = cih * 32 + kg * 8 + e;
            ((unsigned short*)&v)[e] = f32_to_bf16(src[(size_t)cout * 576 + ci * 9 + tap]);
        }
        *(short8*)&dst[(size_t)s * 8] = v;
    }
}

// 3x3 conv (pad=1) + BN + ReLU via bf16 MFMA. r13-r17-validated core.
// NEW: float4-coalesced input staging (was 45 scalar plane-strided loads/thread).
__global__ __launch_bounds__(256) void conv3x3_mfma(
    const float* __restrict__ in,    // [B,64,192,192] f32
    const unsigned short* __restrict__ wfrag,  // [4][18][64][8] bf16 fragment-ordered
    const float* __restrict__ bias,  // [64]
    const float* __restrict__ bn_g, const float* __restrict__ bn_be,
    const float* __restrict__ bn_m, const float* __restrict__ bn_v,
    unsigned short* __restrict__ out)  // [B,192,192,64] bf16 bits (workspace)
{
    __shared__ unsigned short win[10 * 18 * NPAD];   // 25.9 KB bf16 [row][col][ci]
    const int t  = threadIdx.x;
    const int x0 = blockIdx.x << 4, y0 = blockIdx.y << 3;
    const int b  = blockIdx.z;
    const float* inb = in + (size_t)b * 64 * 36864;

    // Edge columns never produced by the clamped reads: pre-zero (no race).
    if (x0 == 0) {
        for (int i = t; i < 640; i += 256) {
            int ci = i & 63, row = i >> 6;
            win[(row * 18 + 0) * NPAD + ci] = 0;
        }
    } else if (x0 == 176) {
        for (int i = t; i < 640; i += 256) {
            int ci = i & 63, row = i >> 6;
            win[(row * 18 + 17) * NPAD + ci] = 0;
        }
    }

    // Coalesced staging: q = p*6 + j, p=(row,ci), j = 6 float4s covering window.
    const int gxs = (x0 == 0) ? 0 : ((x0 == 176) ? 168 : x0 - 4);   // aligned, in-image
#pragma unroll
    for (int it = 0; it < 15; ++it) {
        int q = t + (it << 8);               // 0..3839
        int p = q / 6, j = q - p * 6;
        int ci = p & 63, row = p >> 6;
        int gy = y0 - 1 + row;
        bool rowok = (gy >= 0 && gy < 192);
        int gya = rowok ? gy : (gy < 0 ? 0 : 191);
        int gxa = gxs + j * 4;               // 16B-aligned, fully in-image
        f32x4 v = *(const f32x4*)(inb + (size_t)ci * 36864 + gya * 192 + gxa);
#pragma unroll
        for (int e = 0; e < 4; ++e) {
            int col = gxa + e - (x0 - 1);
            if (col >= 0 && col < 18)
                win[(row * 18 + col) * NPAD + ci] = f32_to_bf16(rowok ? v[e] : 0.f);
        }
    }

    const int wv = t >> 6, l = t & 63;
    const int n  = l & 15, kg = l >> 4;
    const int cout = wv * 16 + n;

    // coalesced fragment loads (r17)
    short8 bfrag[18];
    const unsigned short* wf = wfrag + (size_t)wv * 9216 + l * 8;
#pragma unroll
    for (int kc = 0; kc < 18; ++kc)
        bfrag[kc] = *(const short8*)&wf[kc * 512];

    const float inv = bn_g[cout] / sqrtf(bn_v[cout] + EPSf);
    const float sh  = (bias[cout] - bn_m[cout]) * inv + bn_be[cout];

    f32x4 acc[8];
#pragma unroll
    for (int mt = 0; mt < 8; ++mt) acc[mt] = (f32x4){0.f, 0.f, 0.f, 0.f};

    __syncthreads();

#pragma unroll
    for (int kc = 0; kc < 18; ++kc) {
        int cih = kc & 1, tap = kc >> 1;
        int ky = tap / 3, kx = tap - ky * 3;
        const int cbase = cih * 32 + kg * 8;
        const int col = n + kx;
#pragma unroll
        for (int mt = 0; mt < 8; ++mt) {
            const unsigned short* ap = &win[((mt + ky) * 18 + col) * NPAD + cbase];
            short8 a = *(const short8*)ap;
            acc[mt] = __builtin_amdgcn_mfma_f32_16x16x32_bf16(a, bfrag[kc], acc[mt], 0, 0, 0);
        }
    }

    const size_t pbase = (size_t)b * 36864;
#pragma unroll
    for (int mt = 0; mt < 8; ++mt) {
#pragma unroll
        for (int r = 0; r < 4; ++r) {
            int pxx = kg * 4 + r;
            float v = fmaf(acc[mt][r], inv, sh);
            out[(pbase + (size_t)(y0 + mt) * 192 + x0 + pxx) * 64 + cout] =
                f32_to_bf16(v > 0.f ? v : 0.f);
        }
    }
}

// Fused corr(R=4) + 1x1 conv, full MFMA — EXACT round-16 version (validated).
__global__ __launch_bounds__(256) void corr_conv1x1_mfma(
    const unsigned short* __restrict__ f1, const unsigned short* __restrict__ f2,
    const float* __restrict__ qw,    // [64][145]
    const float* __restrict__ qb,
    const float* __restrict__ qg, const float* __restrict__ qbe,
    const float* __restrict__ qm, const float* __restrict__ qv,
    float* __restrict__ out)         // [B,64,192,192] f32
{
    __shared__ unsigned short smem[20736 + 64 * CSTR];   // 62976 B
    unsigned short* f2w  = smem;            // [12r][24u][72c-pad]
    unsigned short* cbuf = smem + 20736;    // [64px][168]: corr[0..81) | 0 | f1[88..152) | 0

    const int t  = threadIdx.x;
    const int x0 = blockIdx.x << 4, y0 = blockIdx.y << 2;
    const int b  = blockIdx.z;
    const int wv = t >> 6, l = t & 63;
    const int n15 = l & 15, kg = l >> 4, hi4 = kg << 2;
    const size_t pbase = (size_t)b * 36864;

#pragma unroll
    for (int i = 0; i < 9; ++i) {
        int q = t + (i << 8);                 // 0..2303
        int r = q / 192, rem = q - r * 192;
        int u = rem >> 3, j = rem & 7;
        int gy = y0 - 4 + r, gx = x0 - 4 + u;
        short8 v = {0, 0, 0, 0, 0, 0, 0, 0};
        if (gy >= 0 && gy < 192 && gx >= 0 && gx < 192)
            v = *(const short8*)&f2[(pbase + (size_t)gy * 192 + gx) * 64 + j * 8];
        *(short8*)&f2w[(r * 24 + u) * NPAD + j * 8] = v;
    }
#pragma unroll
    for (int i = 0; i < 2; ++i) {
        int q = t + (i << 8);                 // 0..511
        int px = q >> 3, j = q & 7;
        int gy = y0 + (px >> 4), gx = x0 + (px & 15);
        short8 v = *(const short8*)&f1[(pbase + (size_t)gy * 192 + gx) * 64 + j * 8];
        *(short8*)&cbuf[px * CSTR + 88 + j * 8] = v;
    }
    if (t < 64) {
#pragma unroll
        for (int d = 81; d < 88; ++d)  cbuf[t * CSTR + d] = 0;
#pragma unroll
        for (int d = 152; d < 168; ++d) cbuf[t * CSTR + d] = 0;
    }

    const int cout_a = wv * 16 + n15;
    short8 w2[5];
#pragma unroll
    for (int s = 0; s < 5; ++s) {
        short8 v;
#pragma unroll
        for (int e = 0; e < 8; ++e) {
            int k = s * 32 + kg * 8 + e;
            float w = 0.f;
            if (k < 81)                  w = qw[cout_a * 145 + k];
            else if (k >= 88 && k < 152) w = qw[cout_a * 145 + k - 7];
            ((unsigned short*)&v)[e] = f32_to_bf16(w);
        }
        w2[s] = v;
    }
    float inv4[4], sh4[4];
#pragma unroll
    for (int r = 0; r < 4; ++r) {
        int c = wv * 16 + hi4 + r;
        inv4[r] = qg[c] / sqrtf(qv[c] + EPSf);
        sh4[r]  = (qb[c] - qm[c]) * inv4[r] + qbe[c];
    }

    __syncthreads();

    const int ty = wv, tx = n15;
    short8 bfr0 = *(const short8*)&cbuf[(ty * 16 + n15) * CSTR + 88 + kg * 8];
    short8 bfr1 = *(const short8*)&cbuf[(ty * 16 + n15) * CSTR + 120 + kg * 8];
    const int rowb = (ty * 16 + tx) * CSTR;
#pragma unroll
    for (int Mt = 0; Mt < 14; ++Mt) {
        int row = ty * 24 + Mt * 16 + n15;    // = (ty+bb)*24 + u
        short8 a0 = *(const short8*)&f2w[row * NPAD + kg * 8];
        short8 a1 = *(const short8*)&f2w[row * NPAD + 32 + kg * 8];
        f32x4 acc = (f32x4){0.f, 0.f, 0.f, 0.f};
        acc = __builtin_amdgcn_mfma_f32_16x16x32_bf16(a0, bfr0, acc, 0, 0, 0);
        acc = __builtin_amdgcn_mfma_f32_16x16x32_bf16(a1, bfr1, acc, 0, 0, 0);
#pragma unroll
        for (int r = 0; r < 4; ++r) {
            int m  = Mt * 16 + hi4 + r;       // D row
            int bb = m / 24;
            int u  = m - bb * 24;
            int a  = u - tx;
            if (m < 216 && a >= 0 && a <= 8)
                cbuf[rowb + a * 9 + bb] = f32_to_bf16(acc[r] * 0.125f);
        }
    }
    __syncthreads();

    f32x4 acc2[4];
#pragma unroll
    for (int Nt = 0; Nt < 4; ++Nt) {
        acc2[Nt] = (f32x4){0.f, 0.f, 0.f, 0.f};
#pragma unroll
        for (int s = 0; s < 5; ++s) {
            short8 bfr = *(const short8*)&cbuf[(Nt * 16 + n15) * CSTR + s * 32 + kg * 8];
            acc2[Nt] = __builtin_amdgcn_mfma_f32_16x16x32_bf16(w2[s], bfr, acc2[Nt], 0, 0, 0);
        }
    }
#pragma unroll
    for (int Nt = 0; Nt < 4; ++Nt) {
        int gy = y0 + Nt, gx = x0 + n15;
#pragma unroll
        for (int r = 0; r < 4; ++r) {
            int c = wv * 16 + hi4 + r;
            float v = fmaf(acc2[Nt][r], inv4[r], sh4[r]);
            out[((size_t)(b * 64 + c)) * 36864 + (size_t)gy * 192 + gx] = v > 0.f ? v : 0.f;
        }
    }
}

extern "C" void kernel_launch(void* const* d_in, const int* in_sizes, int n_in,
                              void* d_out, int out_size, void* d_ws, size_t ws_size,
                              hipStream_t stream) {
    float* out = (float*)d_out;   // reference output dtype is float32

    // ws: f1 | f2, each [4][192][192][64] bf16 (channel-last) = 18.87 MB
    unsigned short* f1 = (unsigned short*)d_ws;
    unsigned short* f2 = f1 + (size_t)4 * 64 * 36864;

    // Weight fragments in the TAIL of d_out (consumed by convs, then overwritten).
    unsigned short* wfK = (unsigned short*)d_out + 18800640;  // byte 37601280
    unsigned short* wfQ = wfK + 36864;                        // ends at 37748736

    prep_wfrag<<<dim3(2), 256, 0, stream>>>(
        (const float*)d_in[2], (const float*)d_in[8], wfK, wfQ);

    dim3 cgrid(12, 24, 4);
    conv3x3_mfma<<<cgrid, 256, 0, stream>>>(
        (const float*)d_in[0], wfK, (const float*)d_in[3],
        (const float*)d_in[4], (const float*)d_in[5], (const float*)d_in[6],
        (const float*)d_in[7], f1);
    conv3x3_mfma<<<cgrid, 256, 0, stream>>>(
        (const float*)d_in[1], wfQ, (const float*)d_in[9],
        (const float*)d_in[10], (const float*)d_in[11], (const float*)d_in[12],
        (const float*)d_in[13], f2);

    dim3 ggrid(12, 48, 4);
    corr_conv1x1_mfma<<<ggrid, 256, 0, stream>>>(
        f1, f2,
        (const float*)d_in[14], (const float*)d_in[15], (const float*)d_in[16],
        (const float*)d_in[17], (const float*)d_in[18], (const float*)d_in[19],
        out);
}